// Round 17
// baseline (71.478 us; speedup 1.0000x reference)
//
#include <hip/hip_runtime.h>
#include <hip/hip_bf16.h>
#include <math.h>

#define NBINS   129
#define NFFT    256
#define WINL    768
#define TFRAMES 4096
#define OUTL    523640          // 4096*128 - 648
#define NQUADS  (OUTL / 4)      // 130910
#define SHIFT   648
#define WSEG    26
#define CHUNK   (WSEG * 128)
#define NCHUNK  ((OUTL + CHUNK - 1) / CHUNK)   // 158
#define FF      32              // frames per tile (kernel A)
#define TPB     4               // tiles per block (kernel A pipeline)
#define FFS     32              // frames per block (fused fallback)

#define KDIM    288             // 258 real K padded to 9*32
#define KROW    296             // B row stride (ushorts); %8==0
#define GROW    268             // fused-path G row stride
#define WBYTES  (16 * 9 * 64 * 16)               // 147456 B packed twiddles
#define GBYTES  ((size_t)16 * TFRAMES * 256 * 2) // 33.55 MB G buffer
#define NSTG    17              // fallback staging iters (32 frames)
#define NF4     5               // ceil(129*8 / 256) float4-pair staging iters

typedef __attribute__((ext_vector_type(8))) short bf16x8;   // 8 ushorts = 16 B
typedef __attribute__((ext_vector_type(4))) float f32x4;

static __device__ __forceinline__ ushort f2bf(float x) {
    union { float f; unsigned u; } v; v.f = x;
    unsigned r = v.u + 0x7FFFu + ((v.u >> 16) & 1u);
    return (ushort)(r >> 16);
}
static __device__ __forceinline__ float bf2f(ushort u) {
    union { unsigned u_; float f; } g; g.u_ = ((unsigned)u) << 16; return g.f;
}

// ---- pre-kernel: W[m][kappa] packed in mfma A-fragment order ----------------
__global__ void build_w_kernel(ushort* __restrict__ wp)
{
    const int gid  = blockIdx.x * 256 + threadIdx.x;    // 0..9215
    const int lane = gid & 63;
    const int mtks = gid >> 6;
    const int ks   = mtks % 9;
    const int mt   = mtks / 9;
    const int m    = mt * 16 + (lane & 15);
    const int kb   = ks * 32 + ((lane >> 4) << 3);

    ushort o[8];
    #pragma unroll
    for (int e = 0; e < 8; ++e) {
        const int kap = kb + e;
        float val = 0.f;
        if (kap < 258) {
            const int k = kap >> 1;
            float s, c;
            sincospif((float)(k * (m + 1)) * (1.0f / 128.0f), &s, &c);
            if (kap & 1)  val = (k >= 1 && k <= 127) ? s * (2.0f / 256.0f) : 0.f;
            else          val = (k == 0 || k == 128) ? c * (1.0f / 256.0f)
                                                     : c * (2.0f / 256.0f);
        }
        o[e] = f2bf(val);
    }
    int4 pk;
    pk.x = o[0] | (o[1] << 16); pk.y = o[2] | (o[3] << 16);
    pk.z = o[4] | (o[5] << 16); pk.w = o[6] | (o[7] << 16);
    ((int4*)wp)[gid] = pk;
}

// ---- kernel A: producer/consumer DFT GEMM ----------------------------------
// 512 threads: waves 0-3 = consumers (GEMM tile i from LDS, scatter G);
// waves 4-7 = producers (stage tile i+1 into the other LDS buffer).
// One uniform barrier per tile; stage stalls confined to producer waves.
__global__ __launch_bounds__(512, 4)
void pfb_dft_pc_kernel(const float* __restrict__ gre, const float* __restrict__ gim,
                       const ushort* __restrict__ wp, ushort* __restrict__ Gg)
{
    __shared__ ushort s_B[2][FF * KROW];               // 2 x 18944 = 37888 B

    const int tid  = threadIdx.x;                      // 0..511
    const int wave = tid >> 6;                         // 0..7
    const int bc   = blockIdx.y;
    const int tbase = blockIdx.x * (TPB * FF);
    const size_t specBase = (size_t)bc * NBINS * TFRAMES;
    const float4* gre4 = (const float4*)(gre + specBase);
    const float4* gim4 = (const float4*)(gim + specBase);

    const bool producer = (wave >= 4);
    const int  ptid = tid - 256;                       // producer-local 0..255

    float4 vr4[NF4], vi4[NF4];

    auto LOAD = [&](int tile) {
        const int tt0 = tbase + tile * FF;
        #pragma unroll
        for (int r = 0; r < NF4; ++r) {
            const int idx4 = ptid + r * 256;
            float4 a = {0.f, 0.f, 0.f, 0.f}, b = {0.f, 0.f, 0.f, 0.f};
            if (idx4 < NBINS * (FF / 4)) {
                const int k = idx4 >> 3, f4 = idx4 & 7;
                const size_t o4 = (size_t)k * (TFRAMES / 4) + (size_t)(tt0 >> 2) + f4;
                a = gre4[o4]; b = gim4[o4];
            }
            vr4[r] = a; vi4[r] = b;
        }
    };
    auto WLDS = [&](int buf) {
        #pragma unroll
        for (int r = 0; r < NF4; ++r) {
            const int idx4 = ptid + r * 256;
            if (idx4 < NBINS * (FF / 4)) {
                const int k = idx4 >> 3, f4 = idx4 & 7;
                const float rr[4] = {vr4[r].x, vr4[r].y, vr4[r].z, vr4[r].w};
                const float ii[4] = {vi4[r].x, vi4[r].y, vi4[r].z, vi4[r].w};
                #pragma unroll
                for (int j = 0; j < 4; ++j) {
                    __hip_bfloat162 p = __float22bfloat162_rn(make_float2(rr[j], ii[j]));
                    *(__hip_bfloat162*)&s_B[buf][(4 * f4 + j) * KROW + 2 * k] = p;
                }
            }
        }
    };

    // prologue: zero-pad kappa 258..295 in BOTH buffers; producers stage tile 0
    for (int idx = tid; idx < 2 * FF * (KROW - 258); idx += 512) {
        const int bu  = idx / (FF * (KROW - 258));
        const int rem = idx - bu * (FF * (KROW - 258));
        const int f = rem / (KROW - 258), r2 = rem - f * (KROW - 258);
        s_B[bu][f * KROW + 258 + r2] = 0;
    }
    if (producer) { LOAD(0); WLDS(0); }
    __syncthreads();

    // consumer constants
    const int lane = tid & 63;
    const int brow = lane & 15;
    const int kq   = lane >> 4;
    const ushort* wbase0 = wp + ((size_t)(wave * 4) * 9 * 64 + (size_t)lane) * 8;

    #pragma unroll 1
    for (int i = 0; i < TPB; ++i) {
        if (producer) {
            if (i + 1 < TPB) { LOAD(i + 1); WLDS((i + 1) & 1); }
        } else {
            const ushort* sB = s_B[i & 1];
            f32x4 acc[4][2];
            #pragma unroll
            for (int mi = 0; mi < 4; ++mi)
                #pragma unroll
                for (int nt = 0; nt < 2; ++nt)
                    acc[mi][nt] = (f32x4){0.f, 0.f, 0.f, 0.f};

            #pragma unroll
            for (int ks = 0; ks < 9; ++ks) {
                const bf16x8 b0 = *(const bf16x8*)&sB[brow * KROW + ks * 32 + (kq << 3)];
                const bf16x8 b1 = *(const bf16x8*)&sB[(16 + brow) * KROW + ks * 32 + (kq << 3)];
                #pragma unroll
                for (int mi = 0; mi < 4; ++mi) {
                    const bf16x8 aw = *(const bf16x8*)(wbase0 + mi * 4608 + ks * 512);
                    acc[mi][0] = __builtin_amdgcn_mfma_f32_16x16x32_bf16(aw, b0, acc[mi][0], 0, 0, 0);
                    acc[mi][1] = __builtin_amdgcn_mfma_f32_16x16x32_bf16(aw, b1, acc[mi][1], 0, 0, 0);
                }
            }

            // direct global writeback (D: row f = frame, cols m0..m0+3)
            ushort* gout = Gg + ((size_t)bc * TFRAMES + tbase + i * FF) * NFFT;
            #pragma unroll
            for (int mi = 0; mi < 4; ++mi) {
                const int m0 = (wave * 4 + mi) * 16 + (kq << 2);
                #pragma unroll
                for (int nt = 0; nt < 2; ++nt) {
                    const int f = nt * 16 + brow;
                    __hip_bfloat162 lo = __float22bfloat162_rn(make_float2(acc[mi][nt].x, acc[mi][nt].y));
                    __hip_bfloat162 hi = __float22bfloat162_rn(make_float2(acc[mi][nt].z, acc[mi][nt].w));
                    uint2 pk; pk.x = *(unsigned*)&lo; pk.y = *(unsigned*)&hi;
                    *(uint2*)&gout[f * NFFT + m0] = pk;
                }
            }
        }
        __syncthreads();
    }
}

// ---- kernel B: overlap-add streamer, 4 outputs/thread x 2 -------------------
__global__ __launch_bounds__(256, 8)
void pfb_oa_kernel(const ushort* __restrict__ Gg, const float* __restrict__ glpf,
                   float* __restrict__ out)
{
    const int tid = threadIdx.x;
    const int bc  = blockIdx.y;
    const int h0  = blockIdx.x * 512 + tid;        // quad index

    const int b = (4 * h0 + SHIFT) & 127;          // mult of 4; invariant over j
    float4 lw[6];
    #pragma unroll
    for (int p = 0; p < 6; ++p) lw[p] = *(const float4*)&glpf[(p << 7) + b];

    const ushort* Gb = Gg + (size_t)bc * TFRAMES * NFFT;
    const size_t outBase = (size_t)bc * OUTL;

    #pragma unroll
    for (int j = 0; j < 2; ++j) {
        const int h = h0 + j * 256;
        int a = (4 * h + SHIFT) >> 7;
        if (a > TFRAMES - 1) a = TFRAMES - 1;      // clamp keeps loads in-bounds
        float s0 = 0.f, s1 = 0.f, s2 = 0.f, s3 = 0.f;
        #pragma unroll
        for (int p = 0; p < 6; ++p) {
            const ushort4 q = *(const ushort4*)&Gb[(size_t)(a - p) * NFFT + b + ((p & 1) << 7)];
            s0 += lw[p].x * bf2f(q.x);
            s1 += lw[p].y * bf2f(q.y);
            s2 += lw[p].z * bf2f(q.z);
            s3 += lw[p].w * bf2f(q.w);
        }
        if (h < NQUADS) {
            float4 o;
            o.x = s0 * (-32768.0f); o.y = s1 * (-32768.0f);
            o.z = s2 * (-32768.0f); o.w = s3 * (-32768.0f);
            *(float4*)&out[outBase + 4 * h] = o;
        }
    }
}

// ---- fused fallback (round-5 path, used only if ws too small) ---------------
__global__ __launch_bounds__(256, 4)
void pfb_mfma_kernel(const float* __restrict__ gre, const float* __restrict__ gim,
                     const float* __restrict__ glpf, const ushort* __restrict__ wp,
                     float* __restrict__ out)
{
    __shared__ ushort s_bufu[FFS * KROW];
    __shared__ float  s_lpf[WINL];
    ushort* s_Bu = s_bufu;
    ushort (*s_G)[GROW] = (ushort (*)[GROW])s_bufu;

    const int q   = blockIdx.x;
    const int bc  = blockIdx.y;
    const int tid = threadIdx.x;
    const int t0  = WSEG * q;
    const size_t specBase = (size_t)bc * NBINS * TFRAMES;

    for (int idx = tid; idx < WINL; idx += 256) s_lpf[idx] = glpf[idx];

    float vr[NSTG], vi[NSTG];
    #pragma unroll
    for (int r = 0; r < NSTG; ++r) {
        const int idx = tid + r * 256;
        const int k = idx >> 5, f = idx & 31;
        const int t = t0 + f;
        const bool ok = (idx < NBINS * FFS) && (t < TFRAMES);
        float a = 0.f, bb = 0.f;
        if (ok) {
            const size_t g = specBase + (size_t)k * TFRAMES + (size_t)t;
            a = gre[g]; bb = gim[g];
        }
        vr[r] = a; vi[r] = bb;
    }
    #pragma unroll
    for (int r = 0; r < NSTG; ++r) {
        const int idx = tid + r * 256;
        if (idx < NBINS * FFS) {
            const int k = idx >> 5, f = idx & 31;
            __hip_bfloat162 p = __float22bfloat162_rn(make_float2(vr[r], vi[r]));
            *(__hip_bfloat162*)&s_Bu[f * KROW + 2 * k] = p;
        }
    }
    for (int idx = tid; idx < FFS * (KROW - 258); idx += 256) {
        const int f = idx / (KROW - 258), r = idx - f * (KROW - 258);
        s_Bu[f * KROW + 258 + r] = 0;
    }
    __syncthreads();

    const int lane = tid & 63;
    const int wid  = tid >> 6;
    const int brow = lane & 15;
    const int kgrp = (lane >> 4) << 3;

    bf16x8 bfrag[2][9];
    #pragma unroll
    for (int nt = 0; nt < 2; ++nt)
        #pragma unroll
        for (int ks = 0; ks < 9; ++ks)
            bfrag[nt][ks] = *(const bf16x8*)&s_Bu[(nt * 16 + brow) * KROW + ks * 32 + kgrp];

    f32x4 acc[4][2];
    #pragma unroll
    for (int mi = 0; mi < 4; ++mi)
        #pragma unroll
        for (int nt = 0; nt < 2; ++nt)
            acc[mi][nt] = (f32x4){0.f, 0.f, 0.f, 0.f};

    #pragma unroll 1
    for (int mi = 0; mi < 4; ++mi) {
        const ushort* wbase = wp + ((size_t)((wid * 4 + mi) * 9) * 64 + lane) * 8;
        #pragma unroll
        for (int ks = 0; ks < 9; ++ks) {
            const bf16x8 aw = *(const bf16x8*)(wbase + ks * 512);
            acc[mi][0] = __builtin_amdgcn_mfma_f32_16x16x32_bf16(aw, bfrag[0][ks], acc[mi][0], 0, 0, 0);
            acc[mi][1] = __builtin_amdgcn_mfma_f32_16x16x32_bf16(aw, bfrag[1][ks], acc[mi][1], 0, 0, 0);
        }
    }
    __syncthreads();

    #pragma unroll
    for (int mi = 0; mi < 4; ++mi) {
        const int m0 = (wid * 4 + mi) * 16 + ((lane >> 4) << 2);
        #pragma unroll
        for (int nt = 0; nt < 2; ++nt) {
            const int f = nt * 16 + brow;
            __hip_bfloat162 lo = __float22bfloat162_rn(make_float2(acc[mi][nt].x, acc[mi][nt].y));
            __hip_bfloat162 hi = __float22bfloat162_rn(make_float2(acc[mi][nt].z, acc[mi][nt].w));
            uint2 pk; pk.x = *(unsigned*)&lo; pk.y = *(unsigned*)&hi;
            *(uint2*)&s_G[f][m0] = pk;
        }
    }
    __syncthreads();

    const size_t outBase = (size_t)bc * OUTL;
    const int i0 = q * CHUNK;
    #pragma unroll 1
    for (int r = 0; r < 13; ++r) {
        const int i = i0 + r * 256 + tid;
        const int s = i + SHIFT;
        const int tlo = (s - 640) >> 7;
        int thi = s >> 7;
        if (thi > t0 + FFS - 1) thi = t0 + FFS - 1;
        if (thi > TFRAMES - 1) thi = TFRAMES - 1;
        float sum = 0.f;
        #pragma unroll
        for (int u = 0; u < 6; ++u) {
            const int t  = tlo + u;
            int jj = s - (t << 7);
            if (jj < 0) jj = 0;
            const float w = s_lpf[jj];
            sum += (t <= thi) ? w * bf2f(s_G[t - t0][jj & 255]) : 0.f;
        }
        if (i < OUTL) out[outBase + i] = sum * (-32768.0f);
    }
}

extern "C" void kernel_launch(void* const* d_in, const int* in_sizes, int n_in,
                              void* d_out, int out_size, void* d_ws, size_t ws_size,
                              hipStream_t stream)
{
    const float* gre  = (const float*)d_in[0];
    const float* gim  = (const float*)d_in[1];
    const float* glpf = (const float*)d_in[2];
    float* out = (float*)d_out;

    if (ws_size >= (size_t)WBYTES + GBYTES) {
        ushort* wp = (ushort*)d_ws;
        ushort* Gg = (ushort*)((char*)d_ws + WBYTES);
        build_w_kernel<<<36, 256, 0, stream>>>(wp);
        dim3 gridA(TFRAMES / (TPB * FF), 16);         // 32 x 16, 512-thread blocks
        pfb_dft_pc_kernel<<<gridA, 512, 0, stream>>>(gre, gim, wp, Gg);
        dim3 gridB((NQUADS + 511) / 512, 16);         // 256 x 16
        pfb_oa_kernel<<<gridB, 256, 0, stream>>>(Gg, glpf, out);
    } else if (ws_size >= (size_t)WBYTES) {
        ushort* wp = (ushort*)d_ws;
        build_w_kernel<<<36, 256, 0, stream>>>(wp);
        dim3 grid(NCHUNK, 16);
        pfb_mfma_kernel<<<grid, 256, 0, stream>>>(gre, gim, glpf, wp, out);
    }
}

// Round 18
// 63.321 us; speedup vs baseline: 1.1288x; 1.1288x over previous
//
#include <hip/hip_runtime.h>
#include <hip/hip_bf16.h>
#include <math.h>

#define NBINS   129
#define NFFT    256
#define WINL    768
#define TFRAMES 4096
#define OUTL    523640          // 4096*128 - 648
#define SHIFT   648
#define NA      32              // output frames (a) per block
#define FSTAGE  40              // frames staged: NA + 5 halo, padded to mult of 4
#define NQ      128             // ceil((4095-5+1)/32): a0 = 5+32q covers a in [5,4095]
#define KROW    296             // S row stride (ushorts); %8==0, 2-way banks max
#define WFRAGS  (6 * 8 * 9)     // p x mt x ks = 432 A-fragments
#define WBYTES  (WFRAGS * 64 * 16)   // 442368 B packed C_p twiddles
#define NF4     6               // ceil(129*10 / 256) float4 staging iters
#define WSEGF   26              // f32 fallback
#define CHUNKF  (WSEGF * 128)
#define NCHUNKF ((OUTL + CHUNKF - 1) / CHUNKF)

typedef __attribute__((ext_vector_type(8))) short bf16x8;   // 16 bytes
typedef __attribute__((ext_vector_type(4))) float f32x4;

static __device__ __forceinline__ ushort f2bf(float x) {
    union { float f; unsigned u; } v; v.f = x;
    unsigned r = v.u + 0x7FFFu + ((v.u >> 16) & 1u);
    return (ushort)(r >> 16);
}

// ---- pre-kernel: C_p[b][kappa] = -32768*lpf[b+128p]*W[(b+128p)&255][kappa] --
// frag index = (p*8 + mt)*9 + ks; lane gives row b = mt*16+(lane&15),
// kappa-run = ks*32 + (lane>>4)*8 + e.
__global__ void build_w_kernel(const float* __restrict__ glpf, ushort* __restrict__ wp)
{
    const int gid  = blockIdx.x * 256 + threadIdx.x;    // 0..27647
    const int lane = gid & 63;
    const int frag = gid >> 6;                          // 0..431
    const int ks   = frag % 9;
    const int rem  = frag / 9;
    const int mt   = rem % 8;
    const int p    = rem / 8;
    const int b    = mt * 16 + (lane & 15);             // 0..127
    const int kb   = ks * 32 + ((lane >> 4) << 3);
    const int mw   = b + 128 * (p & 1);                 // W row (b+128p)&255
    const float lv = -32768.0f * glpf[b + 128 * p];

    ushort o[8];
    #pragma unroll
    for (int e = 0; e < 8; ++e) {
        const int kap = kb + e;
        float val = 0.f;
        if (kap < 258) {
            const int k = kap >> 1;
            float s, c;
            sincospif((float)(k * (mw + 1)) * (1.0f / 128.0f), &s, &c);
            if (kap & 1)  val = (k >= 1 && k <= 127) ? s * (2.0f / 256.0f) : 0.f;
            else          val = (k == 0 || k == 128) ? c * (1.0f / 256.0f)
                                                     : c * (2.0f / 256.0f);
        }
        o[e] = f2bf(val * lv);
    }
    int4 pk;
    pk.x = o[0] | (o[1] << 16); pk.y = o[2] | (o[3] << 16);
    pk.z = o[4] | (o[5] << 16); pk.w = o[6] | (o[7] << 16);
    ((int4*)wp)[gid] = pk;
}

// ---- main kernel: ONE GEMM  out[b][a] = sum_{p,ks} C_p[b][.] x S[.][a-p] ----
// Block: 32 output frames x 128 b. Stage 40 frames once -> barrier ->
// free-running GEMM (LDS reads + L2 A-frag loads + MFMA) -> coalesced f32 store.
__global__ __launch_bounds__(256, 6)
void pfb_onegemm_kernel(const float* __restrict__ gre, const float* __restrict__ gim,
                        const ushort* __restrict__ wp, float* __restrict__ out)
{
    __shared__ ushort s_S[FSTAGE * KROW];              // 23680 B

    const int q   = blockIdx.x;                        // 0..127
    const int bc  = blockIdx.y;
    const int tid = threadIdx.x;
    const int fbase = q * NA;                          // staged frames fbase..fbase+39
    const size_t specBase = (size_t)bc * NBINS * TFRAMES;
    const float4* gre4 = (const float4*)(gre + specBase);
    const float4* gim4 = (const float4*)(gim + specBase);

    // ---- stage: float4 loads (4 frames each); frames >= 4096 zero-filled ----
    float4 vr4[NF4], vi4[NF4];
    #pragma unroll
    for (int r = 0; r < NF4; ++r) {
        const int idx4 = tid + r * 256;
        float4 a = {0.f, 0.f, 0.f, 0.f}, b = {0.f, 0.f, 0.f, 0.f};
        if (idx4 < NBINS * (FSTAGE / 4)) {
            const int k = idx4 / (FSTAGE / 4), f4 = idx4 % (FSTAGE / 4);
            if (fbase + 4 * f4 < TFRAMES) {
                const size_t o4 = (size_t)k * (TFRAMES / 4) + (size_t)(fbase >> 2) + f4;
                a = gre4[o4]; b = gim4[o4];
            }
        }
        vr4[r] = a; vi4[r] = b;
    }
    #pragma unroll
    for (int r = 0; r < NF4; ++r) {
        const int idx4 = tid + r * 256;
        if (idx4 < NBINS * (FSTAGE / 4)) {
            const int k = idx4 / (FSTAGE / 4), f4 = idx4 % (FSTAGE / 4);
            const float rr[4] = {vr4[r].x, vr4[r].y, vr4[r].z, vr4[r].w};
            const float ii[4] = {vi4[r].x, vi4[r].y, vi4[r].z, vi4[r].w};
            #pragma unroll
            for (int j = 0; j < 4; ++j) {
                __hip_bfloat162 p = __float22bfloat162_rn(make_float2(rr[j], ii[j]));
                *(__hip_bfloat162*)&s_S[(4 * f4 + j) * KROW + 2 * k] = p;
            }
        }
    }
    // zero-pad kappa 258..295
    for (int idx = tid; idx < FSTAGE * (KROW - 258); idx += 256) {
        const int f = idx / (KROW - 258), r2 = idx - f * (KROW - 258);
        s_S[f * KROW + 258 + r2] = 0;
    }
    __syncthreads();

    // ---- GEMM: 6 taps x 9 ks; B-operand = staged S at row offset (5-p) ----
    const int lane = tid & 63;
    const int wave = tid >> 6;                         // 0..3
    const int brow = lane & 15;
    const int kq   = lane >> 4;

    f32x4 acc[2][2];
    #pragma unroll
    for (int mi = 0; mi < 2; ++mi)
        #pragma unroll
        for (int nt = 0; nt < 2; ++nt)
            acc[mi][nt] = (f32x4){0.f, 0.f, 0.f, 0.f};

    const ushort* wl = wp + (size_t)lane * 8;
    #pragma unroll
    for (int p = 0; p < 6; ++p) {
        const int ro = 5 - p;
        #pragma unroll
        for (int ks = 0; ks < 9; ++ks) {
            const bf16x8 b0 = *(const bf16x8*)&s_S[(brow + ro) * KROW + ks * 32 + (kq << 3)];
            const bf16x8 b1 = *(const bf16x8*)&s_S[(16 + brow + ro) * KROW + ks * 32 + (kq << 3)];
            #pragma unroll
            for (int mi = 0; mi < 2; ++mi) {
                const int frag = (p * 8 + wave * 2 + mi) * 9 + ks;
                const bf16x8 aw = *(const bf16x8*)(wl + ((size_t)frag << 9));
                acc[mi][0] = __builtin_amdgcn_mfma_f32_16x16x32_bf16(aw, b0, acc[mi][0], 0, 0, 0);
                acc[mi][1] = __builtin_amdgcn_mfma_f32_16x16x32_bf16(aw, b1, acc[mi][1], 0, 0, 0);
            }
        }
    }

    // ---- store: i = 128a - 648 + b; per instr 64 lanes cover 16 full lines ----
    const size_t outBase = (size_t)bc * OUTL;
    const int a0 = fbase + 5;
    #pragma unroll
    for (int mi = 0; mi < 2; ++mi) {
        const int b0c = (wave * 2 + mi) * 16 + (kq << 2);
        #pragma unroll
        for (int nt = 0; nt < 2; ++nt) {
            const int a = a0 + nt * 16 + brow;
            if (a <= TFRAMES - 1 && (a >= 6 || b0c >= 8)) {
                const int i = 128 * a - SHIFT + b0c;
                *(f32x4*)&out[outBase + i] = acc[mi][nt];
            }
        }
    }
}

// ---- fallback: round-1 pure-f32 fused (no workspace needed) -----------------
__global__ __launch_bounds__(256, 2)
void pfb_f32_kernel(const float* __restrict__ gre, const float* __restrict__ gim,
                    const float* __restrict__ glpf, float* __restrict__ out)
{
    __shared__ float s_buf[NBINS * 32 * 2];
    __shared__ float s_lpf[WINL];
    float (*s_re)[32] = (float (*)[32])s_buf;
    float (*s_im)[32] = (float (*)[32])(s_buf + NBINS * 32);
    float (*s_G)[NFFT] = (float (*)[NFFT])s_buf;

    const int q = blockIdx.x, bc = blockIdx.y, tid = threadIdx.x;
    const int t0 = WSEGF * q;
    const size_t specBase = (size_t)bc * NBINS * TFRAMES;

    for (int idx = tid; idx < WINL; idx += 256) s_lpf[idx] = glpf[idx];
    for (int idx = tid; idx < NBINS * 32; idx += 256) {
        const int k = idx >> 5, f = idx & 31;
        const int t = t0 + f;
        float vr = 0.f, vi = 0.f;
        if (t < TFRAMES) {
            const size_t g = specBase + (size_t)k * TFRAMES + (size_t)t;
            vr = gre[g]; vi = gim[g];
        }
        s_re[k][f] = vr; s_im[k][f] = vi;
    }
    __syncthreads();

    const int ng = tid & 63, fg = tid >> 6, f0 = fg * 8;
    float cphi[4], sphi[4], cc[4], ss[4], acc[4][8];
    #pragma unroll
    for (int j = 0; j < 4; ++j) {
        const int m = ng + 64 * j;
        sincospif((float)(m + 1) * (1.0f / 128.0f), &sphi[j], &cphi[j]);
        cc[j] = 1.f; ss[j] = 0.f;
        #pragma unroll
        for (int f = 0; f < 8; ++f) acc[j][f] = 0.f;
    }
    #pragma unroll 2
    for (int k = 1; k <= 127; ++k) {
        const float4 rl = *(const float4*)&s_re[k][f0];
        const float4 rh = *(const float4*)&s_re[k][f0 + 4];
        const float4 il = *(const float4*)&s_im[k][f0];
        const float4 ih = *(const float4*)&s_im[k][f0 + 4];
        #pragma unroll
        for (int j = 0; j < 4; ++j) {
            const float c2 = cc[j] * cphi[j] - ss[j] * sphi[j];
            const float s2 = ss[j] * cphi[j] + cc[j] * sphi[j];
            cc[j] = c2; ss[j] = s2;
            acc[j][0] += rl.x * c2 + il.x * s2;
            acc[j][1] += rl.y * c2 + il.y * s2;
            acc[j][2] += rl.z * c2 + il.z * s2;
            acc[j][3] += rl.w * c2 + il.w * s2;
            acc[j][4] += rh.x * c2 + ih.x * s2;
            acc[j][5] += rh.y * c2 + ih.y * s2;
            acc[j][6] += rh.z * c2 + ih.z * s2;
            acc[j][7] += rh.w * c2 + ih.w * s2;
        }
    }
    float r0[8], r128[8];
    #pragma unroll
    for (int f = 0; f < 8; ++f) { r0[f] = s_re[0][f0 + f]; r128[f] = s_re[128][f0 + f]; }
    __syncthreads();
    #pragma unroll
    for (int j = 0; j < 4; ++j) {
        const int m = ng + 64 * j;
        const float sgn = (m & 1) ? 1.0f : -1.0f;
        #pragma unroll
        for (int f = 0; f < 8; ++f)
            s_G[f0 + f][m] = (r0[f] + 2.0f * acc[j][f] + sgn * r128[f]) * (1.0f / 256.0f);
    }
    __syncthreads();
    const size_t outBase = (size_t)bc * OUTL;
    const int i0 = q * CHUNKF;
    #pragma unroll 1
    for (int r = 0; r < 13; ++r) {
        const int i = i0 + r * 256 + tid;
        if (i < OUTL) {
            const int s = i + SHIFT;
            int tlo = (s - 640) >> 7;  if (tlo < t0) tlo = t0;
            int thi = s >> 7;
            if (thi > t0 + 31) thi = t0 + 31;
            if (thi > TFRAMES - 1) thi = TFRAMES - 1;
            float sum = 0.f;
            for (int t = tlo; t <= thi; ++t) {
                const int jj = s - (t << 7);
                sum += s_lpf[jj] * s_G[t - t0][jj & 255];
            }
            out[outBase + i] = sum * (-32768.0f);
        }
    }
}

extern "C" void kernel_launch(void* const* d_in, const int* in_sizes, int n_in,
                              void* d_out, int out_size, void* d_ws, size_t ws_size,
                              hipStream_t stream)
{
    const float* gre  = (const float*)d_in[0];
    const float* gim  = (const float*)d_in[1];
    const float* glpf = (const float*)d_in[2];
    float* out = (float*)d_out;

    if (ws_size >= (size_t)WBYTES) {
        ushort* wp = (ushort*)d_ws;
        build_w_kernel<<<WFRAGS / 4, 256, 0, stream>>>(glpf, wp);   // 108 x 256
        dim3 grid(NQ, 16);                                          // 128 x 16
        pfb_onegemm_kernel<<<grid, 256, 0, stream>>>(gre, gim, wp, out);
    } else {
        dim3 grid(NCHUNKF, 16);
        pfb_f32_kernel<<<grid, 256, 0, stream>>>(gre, gim, glpf, out);
    }
}

// Round 19
// 50.055 us; speedup vs baseline: 1.4280x; 1.2650x over previous
//
#include <hip/hip_runtime.h>
#include <hip/hip_bf16.h>
#include <math.h>

#define NBINS   129
#define NFFT    256
#define WINL    768
#define TFRAMES 4096
#define OUTL    523640          // 4096*128 - 648
#define NQUADS  (OUTL / 4)      // 130910
#define SHIFT   648
#define WSEG    26
#define CHUNK   (WSEG * 128)
#define NCHUNK  ((OUTL + CHUNK - 1) / CHUNK)   // 158
#define FF      64              // frames per block (kernel A)
#define FFS     32              // frames per block (fused fallback)

#define KDIM    288             // 258 real K padded to 9*32
#define KROW    296             // B row stride (ushorts); %8==0
#define GROWL   264             // G LDS stride (ushorts): 528B = 4 banks mod 32 -> 2-way
#define GROW    268             // fused-path G row stride
#define WBYTES  (16 * 9 * 64 * 16)               // 147456 B packed twiddles
#define GBYTES  ((size_t)16 * TFRAMES * 256 * 2) // 33.55 MB G buffer
#define NSTG    17              // fallback staging iters (32 frames)
#define NF4     9               // ceil(129*16 / 256) float4 staging iters

typedef __attribute__((ext_vector_type(8))) short bf16x8;   // 8 ushorts = 16 BYTES
typedef __attribute__((ext_vector_type(4))) float f32x4;

static __device__ __forceinline__ ushort f2bf(float x) {
    union { float f; unsigned u; } v; v.f = x;
    unsigned r = v.u + 0x7FFFu + ((v.u >> 16) & 1u);
    return (ushort)(r >> 16);
}
static __device__ __forceinline__ float bf2f(ushort u) {
    union { unsigned u_; float f; } g; g.u_ = ((unsigned)u) << 16; return g.f;
}

// ---- pre-kernel: W[m][kappa] packed in mfma A-fragment order ----------------
__global__ void build_w_kernel(ushort* __restrict__ wp)
{
    const int gid  = blockIdx.x * 256 + threadIdx.x;    // 0..9215
    const int lane = gid & 63;
    const int mtks = gid >> 6;
    const int ks   = mtks % 9;
    const int mt   = mtks / 9;
    const int m    = mt * 16 + (lane & 15);
    const int kb   = ks * 32 + ((lane >> 4) << 3);

    ushort o[8];
    #pragma unroll
    for (int e = 0; e < 8; ++e) {
        const int kap = kb + e;
        float val = 0.f;
        if (kap < 258) {
            const int k = kap >> 1;
            float s, c;
            sincospif((float)(k * (m + 1)) * (1.0f / 128.0f), &s, &c);
            if (kap & 1)  val = (k >= 1 && k <= 127) ? s * (2.0f / 256.0f) : 0.f;
            else          val = (k == 0 || k == 128) ? c * (1.0f / 256.0f)
                                                     : c * (2.0f / 256.0f);
        }
        o[e] = f2bf(val);
    }
    int4 pk;
    pk.x = o[0] | (o[1] << 16); pk.y = o[2] | (o[3] << 16);
    pk.z = o[4] | (o[5] << 16); pk.w = o[6] | (o[7] << 16);
    ((int4*)wp)[gid] = pk;
}

// ---- kernel A: DFT GEMM, 64 frames/block, bank-clean LDS-G, full-line write -
__global__ __launch_bounds__(256, 4)
void pfb_dft_kernel(const float* __restrict__ gre, const float* __restrict__ gim,
                    const ushort* __restrict__ wp, ushort* __restrict__ Gg)
{
    __shared__ ushort s_mem[FF * KROW];                // 37888 B; G (33792 B) aliases
    ushort* s_Bu = s_mem;
    ushort (*s_G)[GROWL] = (ushort (*)[GROWL])s_mem;

    const int t0  = blockIdx.x * FF;
    const int bc  = blockIdx.y;
    const int tid = threadIdx.x;
    const size_t specBase = (size_t)bc * NBINS * TFRAMES;

    // stage: float4 loads (4 frames each), all issued before LDS writes
    const float4* gre4 = (const float4*)(gre + specBase);
    const float4* gim4 = (const float4*)(gim + specBase);
    float4 vr4[NF4], vi4[NF4];
    #pragma unroll
    for (int r = 0; r < NF4; ++r) {
        const int idx4 = tid + r * 256;
        float4 a = {0.f, 0.f, 0.f, 0.f}, b = {0.f, 0.f, 0.f, 0.f};
        if (idx4 < NBINS * (FF / 4)) {
            const int k = idx4 >> 4, f4 = idx4 & 15;
            const size_t o4 = (size_t)k * (TFRAMES / 4) + (size_t)(t0 >> 2) + f4;
            a = gre4[o4]; b = gim4[o4];
        }
        vr4[r] = a; vi4[r] = b;
    }
    #pragma unroll
    for (int r = 0; r < NF4; ++r) {
        const int idx4 = tid + r * 256;
        if (idx4 < NBINS * (FF / 4)) {
            const int k = idx4 >> 4, f4 = idx4 & 15;
            const float rr[4] = {vr4[r].x, vr4[r].y, vr4[r].z, vr4[r].w};
            const float ii[4] = {vi4[r].x, vi4[r].y, vi4[r].z, vi4[r].w};
            #pragma unroll
            for (int j = 0; j < 4; ++j) {
                __hip_bfloat162 p = __float22bfloat162_rn(make_float2(rr[j], ii[j]));
                *(__hip_bfloat162*)&s_Bu[(4 * f4 + j) * KROW + 2 * k] = p;
            }
        }
    }
    for (int idx = tid; idx < FF * (KROW - 258); idx += 256) {
        const int f = idx / (KROW - 258), r2 = idx - f * (KROW - 258);
        s_Bu[f * KROW + 258 + r2] = 0;
    }
    __syncthreads();

    // GEMM: G[256][64] = W[256][288] x B[288][64], ks-outer
    const int lane = tid & 63;
    const int wid  = tid >> 6;
    const int brow = lane & 15;
    const int kq   = lane >> 4;

    f32x4 acc[4][4];
    #pragma unroll
    for (int mi = 0; mi < 4; ++mi)
        #pragma unroll
        for (int nt = 0; nt < 4; ++nt)
            acc[mi][nt] = (f32x4){0.f, 0.f, 0.f, 0.f};

    const ushort* wbase0 = wp + ((size_t)(wid * 4) * 9 * 64 + (size_t)lane) * 8;
    #pragma unroll
    for (int ks = 0; ks < 9; ++ks) {
        bf16x8 bv[4];
        #pragma unroll
        for (int nt = 0; nt < 4; ++nt)
            bv[nt] = *(const bf16x8*)&s_Bu[(nt * 16 + brow) * KROW + ks * 32 + (kq << 3)];
        #pragma unroll
        for (int mi = 0; mi < 4; ++mi) {
            const bf16x8 aw = *(const bf16x8*)(wbase0 + mi * 4608 + ks * 512);
            #pragma unroll
            for (int nt = 0; nt < 4; ++nt)
                acc[mi][nt] = __builtin_amdgcn_mfma_f32_16x16x32_bf16(aw, bv[nt], acc[mi][nt], 0, 0, 0);
        }
    }
    __syncthreads();   // B consumed; alias with s_G

    // D -> LDS (stride 264: 2-way banks, free)
    #pragma unroll
    for (int mi = 0; mi < 4; ++mi) {
        const int m0 = (wid * 4 + mi) * 16 + (kq << 2);
        #pragma unroll
        for (int nt = 0; nt < 4; ++nt) {
            const int f = nt * 16 + brow;
            __hip_bfloat162 lo = __float22bfloat162_rn(make_float2(acc[mi][nt].x, acc[mi][nt].y));
            __hip_bfloat162 hi = __float22bfloat162_rn(make_float2(acc[mi][nt].z, acc[mi][nt].w));
            uint2 pk; pk.x = *(unsigned*)&lo; pk.y = *(unsigned*)&hi;
            *(uint2*)&s_G[f][m0] = pk;
        }
    }
    __syncthreads();

    // coalesced full-line writeback: 64 frames x 256 bf16 = 32 KB contiguous.
    // 16-BYTE (8-ushort) chunks: 2048 chunks total -> 8 iters x 256 threads.
    ushort* gout = Gg + ((size_t)bc * TFRAMES + t0) * NFFT;
    #pragma unroll
    for (int it = 0; it < 8; ++it) {
        const int c = tid + it * 256;          // 0..2047
        const int row = c >> 5, chunk = c & 31;
        *(bf16x8*)&gout[c * 8] = *(const bf16x8*)&s_G[row][chunk * 8];
    }
}

// ---- kernel B: overlap-add streamer, 4 outputs/thread x 2 -------------------
__global__ __launch_bounds__(256, 8)
void pfb_oa_kernel(const ushort* __restrict__ Gg, const float* __restrict__ glpf,
                   float* __restrict__ out)
{
    const int tid = threadIdx.x;
    const int bc  = blockIdx.y;
    const int h0  = blockIdx.x * 512 + tid;        // quad index

    const int b = (4 * h0 + SHIFT) & 127;          // mult of 4; invariant over j
    float4 lw[6];
    #pragma unroll
    for (int p = 0; p < 6; ++p) lw[p] = *(const float4*)&glpf[(p << 7) + b];

    const ushort* Gb = Gg + (size_t)bc * TFRAMES * NFFT;
    const size_t outBase = (size_t)bc * OUTL;

    #pragma unroll
    for (int j = 0; j < 2; ++j) {
        const int h = h0 + j * 256;
        int a = (4 * h + SHIFT) >> 7;
        if (a > TFRAMES - 1) a = TFRAMES - 1;      // clamp keeps loads in-bounds
        float s0 = 0.f, s1 = 0.f, s2 = 0.f, s3 = 0.f;
        #pragma unroll
        for (int p = 0; p < 6; ++p) {
            const ushort4 q = *(const ushort4*)&Gb[(size_t)(a - p) * NFFT + b + ((p & 1) << 7)];
            s0 += lw[p].x * bf2f(q.x);
            s1 += lw[p].y * bf2f(q.y);
            s2 += lw[p].z * bf2f(q.z);
            s3 += lw[p].w * bf2f(q.w);
        }
        if (h < NQUADS) {
            float4 o;
            o.x = s0 * (-32768.0f); o.y = s1 * (-32768.0f);
            o.z = s2 * (-32768.0f); o.w = s3 * (-32768.0f);
            *(float4*)&out[outBase + 4 * h] = o;
        }
    }
}

// ---- fused fallback (round-5 path, used only if ws too small) ---------------
__global__ __launch_bounds__(256, 4)
void pfb_mfma_kernel(const float* __restrict__ gre, const float* __restrict__ gim,
                     const float* __restrict__ glpf, const ushort* __restrict__ wp,
                     float* __restrict__ out)
{
    __shared__ ushort s_bufu[FFS * KROW];
    __shared__ float  s_lpf[WINL];
    ushort* s_Bu = s_bufu;
    ushort (*s_G)[GROW] = (ushort (*)[GROW])s_bufu;

    const int q   = blockIdx.x;
    const int bc  = blockIdx.y;
    const int tid = threadIdx.x;
    const int t0  = WSEG * q;
    const size_t specBase = (size_t)bc * NBINS * TFRAMES;

    for (int idx = tid; idx < WINL; idx += 256) s_lpf[idx] = glpf[idx];

    float vr[NSTG], vi[NSTG];
    #pragma unroll
    for (int r = 0; r < NSTG; ++r) {
        const int idx = tid + r * 256;
        const int k = idx >> 5, f = idx & 31;
        const int t = t0 + f;
        const bool ok = (idx < NBINS * FFS) && (t < TFRAMES);
        float a = 0.f, bb = 0.f;
        if (ok) {
            const size_t g = specBase + (size_t)k * TFRAMES + (size_t)t;
            a = gre[g]; bb = gim[g];
        }
        vr[r] = a; vi[r] = bb;
    }
    #pragma unroll
    for (int r = 0; r < NSTG; ++r) {
        const int idx = tid + r * 256;
        if (idx < NBINS * FFS) {
            const int k = idx >> 5, f = idx & 31;
            __hip_bfloat162 p = __float22bfloat162_rn(make_float2(vr[r], vi[r]));
            *(__hip_bfloat162*)&s_Bu[f * KROW + 2 * k] = p;
        }
    }
    for (int idx = tid; idx < FFS * (KROW - 258); idx += 256) {
        const int f = idx / (KROW - 258), r = idx - f * (KROW - 258);
        s_Bu[f * KROW + 258 + r] = 0;
    }
    __syncthreads();

    const int lane = tid & 63;
    const int wid  = tid >> 6;
    const int brow = lane & 15;
    const int kgrp = (lane >> 4) << 3;

    bf16x8 bfrag[2][9];
    #pragma unroll
    for (int nt = 0; nt < 2; ++nt)
        #pragma unroll
        for (int ks = 0; ks < 9; ++ks)
            bfrag[nt][ks] = *(const bf16x8*)&s_Bu[(nt * 16 + brow) * KROW + ks * 32 + kgrp];

    f32x4 acc[4][2];
    #pragma unroll
    for (int mi = 0; mi < 4; ++mi)
        #pragma unroll
        for (int nt = 0; nt < 2; ++nt)
            acc[mi][nt] = (f32x4){0.f, 0.f, 0.f, 0.f};

    #pragma unroll 1
    for (int mi = 0; mi < 4; ++mi) {
        const ushort* wbase = wp + ((size_t)((wid * 4 + mi) * 9) * 64 + lane) * 8;
        #pragma unroll
        for (int ks = 0; ks < 9; ++ks) {
            const bf16x8 aw = *(const bf16x8*)(wbase + ks * 512);
            acc[mi][0] = __builtin_amdgcn_mfma_f32_16x16x32_bf16(aw, bfrag[0][ks], acc[mi][0], 0, 0, 0);
            acc[mi][1] = __builtin_amdgcn_mfma_f32_16x16x32_bf16(aw, bfrag[1][ks], acc[mi][1], 0, 0, 0);
        }
    }
    __syncthreads();

    #pragma unroll
    for (int mi = 0; mi < 4; ++mi) {
        const int m0 = (wid * 4 + mi) * 16 + ((lane >> 4) << 2);
        #pragma unroll
        for (int nt = 0; nt < 2; ++nt) {
            const int f = nt * 16 + brow;
            __hip_bfloat162 lo = __float22bfloat162_rn(make_float2(acc[mi][nt].x, acc[mi][nt].y));
            __hip_bfloat162 hi = __float22bfloat162_rn(make_float2(acc[mi][nt].z, acc[mi][nt].w));
            uint2 pk; pk.x = *(unsigned*)&lo; pk.y = *(unsigned*)&hi;
            *(uint2*)&s_G[f][m0] = pk;
        }
    }
    __syncthreads();

    const size_t outBase = (size_t)bc * OUTL;
    const int i0 = q * CHUNK;
    #pragma unroll 1
    for (int r = 0; r < 13; ++r) {
        const int i = i0 + r * 256 + tid;
        const int s = i + SHIFT;
        const int tlo = (s - 640) >> 7;
        int thi = s >> 7;
        if (thi > t0 + FFS - 1) thi = t0 + FFS - 1;
        if (thi > TFRAMES - 1) thi = TFRAMES - 1;
        float sum = 0.f;
        #pragma unroll
        for (int u = 0; u < 6; ++u) {
            const int t  = tlo + u;
            int jj = s - (t << 7);
            if (jj < 0) jj = 0;
            const float w = s_lpf[jj];
            sum += (t <= thi) ? w * bf2f(s_G[t - t0][jj & 255]) : 0.f;
        }
        if (i < OUTL) out[outBase + i] = sum * (-32768.0f);
    }
}

extern "C" void kernel_launch(void* const* d_in, const int* in_sizes, int n_in,
                              void* d_out, int out_size, void* d_ws, size_t ws_size,
                              hipStream_t stream)
{
    const float* gre  = (const float*)d_in[0];
    const float* gim  = (const float*)d_in[1];
    const float* glpf = (const float*)d_in[2];
    float* out = (float*)d_out;

    if (ws_size >= (size_t)WBYTES + GBYTES) {
        ushort* wp = (ushort*)d_ws;
        ushort* Gg = (ushort*)((char*)d_ws + WBYTES);
        build_w_kernel<<<36, 256, 0, stream>>>(wp);
        dim3 gridA(TFRAMES / FF, 16);                 // 64 x 16
        pfb_dft_kernel<<<gridA, 256, 0, stream>>>(gre, gim, wp, Gg);
        dim3 gridB((NQUADS + 511) / 512, 16);         // 256 x 16
        pfb_oa_kernel<<<gridB, 256, 0, stream>>>(Gg, glpf, out);
    } else if (ws_size >= (size_t)WBYTES) {
        ushort* wp = (ushort*)d_ws;
        build_w_kernel<<<36, 256, 0, stream>>>(wp);
        dim3 grid(NCHUNK, 16);
        pfb_mfma_kernel<<<grid, 256, 0, stream>>>(gre, gim, glpf, wp, out);
    }
}